// Round 4
// baseline (632.975 us; speedup 1.0000x reference)
//
#include <hip/hip_runtime.h>
#include <hip/hip_bf16.h>

// FlashSVDFFN: out = (gelu((x@U1)@V1 + b1)@U2)@V2 + b2
// pgemm: P = bf16(x)@U1            [16384][256] bf16
// hqgemm: register-dataflow fused H+Q (swapped-operand MFMA, zero LDS)
//         -> qpart[F][16384][256] f32 over F f-slices
// ogemm: out = (sum_j qpart_j)@V2 + b2

typedef __attribute__((ext_vector_type(8))) short bfrag8;     // 8 bf16 fragment
typedef __attribute__((ext_vector_type(4))) float fx4;
typedef __attribute__((ext_vector_type(4))) unsigned short usx4;

#define D_MODEL 1024
#define D_FF    4096
#define RANK    256
#define NROWS   16384
#define PSTR    264
#define XSTR    136

__device__ __forceinline__ unsigned short f2b(float f) {
  union { float f; unsigned u; } v; v.f = f;
  unsigned r = v.u + 0x7FFFu + ((v.u >> 16) & 1u);   // RTNE
  return (unsigned short)(r >> 16);
}

__device__ __forceinline__ float gelu_tanh(float x) {
  float x2 = x * x;
  float y  = 0.7978845608028654f * __builtin_fmaf(0.044715f * x2, x, x);
  float ay = __builtin_fabsf(y);
  float e  = __expf(-2.0f * ay);
  float t  = (1.0f - e) * __builtin_amdgcn_rcpf(1.0f + e);   // tanh(|y|)
  t = __builtin_copysignf(t, y);
  return 0.5f * x * (1.0f + t);
}

// out[c][r] = bf16(in[r][c]); in is R x C row-major.
__global__ void tconv(const float* __restrict__ in, unsigned short* __restrict__ out,
                      int R, int C) {
  __shared__ float t[32][33];
  int c0 = blockIdx.x * 32, r0 = blockIdx.y * 32;
  int tx = threadIdx.x & 31, ty = threadIdx.x >> 5;
#pragma unroll
  for (int i = 0; i < 32; i += 8)
    t[ty + i][tx] = in[(size_t)(r0 + ty + i) * C + c0 + tx];
  __syncthreads();
#pragma unroll
  for (int i = 0; i < 32; i += 8)
    out[(size_t)(c0 + ty + i) * R + r0 + tx] = f2b(t[tx][ty + i]);
}

// U2 [D_FF][RANK] f32 -> u2p [RANK][D_FF] bf16 with k-slot permutation:
// u2p[r2][32t + 8hi + j] = U2[32t + (j>=4)*16 + 4hi + (j&3)][r2]
__global__ void u2repack(const float* __restrict__ in, unsigned short* __restrict__ out) {
  __shared__ float t[32][33];
  int f0 = blockIdx.x * 32, r0 = blockIdx.y * 32;
  int tx = threadIdx.x & 31, ty = threadIdx.x >> 5;
#pragma unroll
  for (int i = 0; i < 32; i += 8)
    t[ty + i][tx] = in[(size_t)(f0 + ty + i) * RANK + r0 + tx];   // t[f_local][r2_local]
  __syncthreads();
  int fl = (((tx & 7) >= 4) ? 16 : 0) + 4 * (tx >> 3) + (tx & 3);
#pragma unroll
  for (int i = 0; i < 32; i += 8)
    out[(size_t)(r0 + ty + i) * D_FF + f0 + tx] = f2b(t[fl][ty + i]);
}

// ---------------- P = bf16(x) @ U1 : [16384][256] bf16 ----------------
__global__ __launch_bounds__(256, 4) void pgemm(
    const float* __restrict__ x, const unsigned short* __restrict__ u1t,
    unsigned short* __restrict__ P)
{
  __shared__ unsigned short xs[32 * XSTR];
  const int tid = threadIdx.x;
  const int w = tid >> 6, lane = tid & 63, lo = lane & 15, hi = lane >> 4;
  const size_t gr0 = (size_t)blockIdx.x * 32;

  fx4 acc[2][4];
#pragma unroll
  for (int mt = 0; mt < 2; ++mt)
#pragma unroll
    for (int nt = 0; nt < 4; ++nt) acc[mt][nt] = fx4{0.f, 0.f, 0.f, 0.f};

  for (int d0 = 0; d0 < D_MODEL; d0 += 128) {
    __syncthreads();
#pragma unroll
    for (int it = 0; it < 4; ++it) {
      int idx = it * 256 + tid;
      int r = idx >> 5, c = (idx & 31) << 2;
      fx4 v = *(const fx4*)(x + (gr0 + r) * D_MODEL + d0 + c);
      usx4 bv; bv[0] = f2b(v[0]); bv[1] = f2b(v[1]); bv[2] = f2b(v[2]); bv[3] = f2b(v[3]);
      *(usx4*)(xs + r * XSTR + c) = bv;
    }
    __syncthreads();
#pragma unroll
    for (int ks = 0; ks < 128; ks += 32) {
      bfrag8 a[2], b[4];
#pragma unroll
      for (int mt = 0; mt < 2; ++mt)
        a[mt] = *(const bfrag8*)(xs + (16 * mt + lo) * XSTR + ks + hi * 8);
#pragma unroll
      for (int nt = 0; nt < 4; ++nt)
        b[nt] = *(const bfrag8*)(u1t + (size_t)(w * 64 + nt * 16 + lo) * D_MODEL + d0 + ks + hi * 8);
#pragma unroll
      for (int mt = 0; mt < 2; ++mt)
#pragma unroll
        for (int nt = 0; nt < 4; ++nt)
          acc[mt][nt] = __builtin_amdgcn_mfma_f32_16x16x32_bf16(a[mt], b[nt], acc[mt][nt], 0, 0, 0);
    }
  }
#pragma unroll
  for (int mt = 0; mt < 2; ++mt)
#pragma unroll
    for (int nt = 0; nt < 4; ++nt)
#pragma unroll
      for (int r = 0; r < 4; ++r)
        P[(gr0 + 16 * mt + 4 * hi + r) * RANK + w * 64 + nt * 16 + lo] = f2b(acc[mt][nt][r]);
}

// -------- fused H+Q, zero LDS, swapped-operand register dataflow --------
// 512 thr = 8 waves; wave w owns rows [gr0+16w, gr0+16w+16). Each wave:
//   hacc = mfma(V1^T frag, P^T frag)  -> lane holds H[row=lo][f=4hi+r]
//   gelu+pack -> B-frag (k-slot perm) -> qacc = mfma(u2p frag, hbq, qacc)
__global__ __launch_bounds__(512, 2) void hqgemm(
    const unsigned short* __restrict__ P,     // [NROWS][RANK] bf16
    const unsigned short* __restrict__ v1t,   // [D_FF][RANK] bf16 = V1^T
    const float* __restrict__ b1,
    const unsigned short* __restrict__ u2p,   // [RANK][D_FF] bf16, k-permuted
    float* __restrict__ qpart,                // [F][NROWS][RANK] f32
    int F)
{
  const int tid = threadIdx.x;
  const int w = tid >> 6, lane = tid & 63, lo = lane & 15, hi = lane >> 4;

  // XCD-aware swizzle: f-slice y -> one XCD group, rows spread within
  int nrb = NROWS / 128;
  int lin = blockIdx.x + blockIdx.y * nrb;
  int rb, j;
  if (F == 2) {
    int xcd = lin & 7, idx = lin >> 3;
    j = xcd >> 2;
    rb = idx * 4 + (xcd & 3);
    if (rb >= nrb) { rb = lin % nrb; j = lin / nrb; }   // safety (nrb%4!=0 case)
  } else { rb = blockIdx.x; j = blockIdx.y; }

  const size_t row = (size_t)rb * 128 + 16 * w + lo;    // this lane's x-row
  const int fbeg = j * (D_FF / F), fend = fbeg + (D_FF / F);

  // P fragments (B-operand, k-slot = 8hi + elem), wave's 16 rows, once.
  bfrag8 pf[8];
#pragma unroll
  for (int ks = 0; ks < 8; ++ks)
    pf[ks] = *(const bfrag8*)(P + row * RANK + ks * 32 + hi * 8);

  fx4 qacc[16];
#pragma unroll
  for (int nt = 0; nt < 16; ++nt) qacc[nt] = fx4{0.f, 0.f, 0.f, 0.f};

  for (int f0 = fbeg; f0 < fend; f0 += 32) {
    fx4 hE = fx4{0.f, 0.f, 0.f, 0.f}, hO = fx4{0.f, 0.f, 0.f, 0.f};
#pragma unroll
    for (int ks = 0; ks < 8; ++ks) {
      bfrag8 vE = *(const bfrag8*)(v1t + (size_t)(f0 + lo) * RANK + ks * 32 + hi * 8);
      bfrag8 vO = *(const bfrag8*)(v1t + (size_t)(f0 + 16 + lo) * RANK + ks * 32 + hi * 8);
      hE = __builtin_amdgcn_mfma_f32_16x16x32_bf16(vE, pf[ks], hE, 0, 0, 0);
      hO = __builtin_amdgcn_mfma_f32_16x16x32_bf16(vO, pf[ks], hO, 0, 0, 0);
    }
    fx4 bE = *(const fx4*)(b1 + f0 + 4 * hi);
    fx4 bO = *(const fx4*)(b1 + f0 + 16 + 4 * hi);
    bfrag8 bq;
#pragma unroll
    for (int r = 0; r < 4; ++r) {
      bq[r]     = (short)f2b(gelu_tanh(hE[r] + bE[r]));
      bq[r + 4] = (short)f2b(gelu_tanh(hO[r] + bO[r]));
    }
#pragma unroll
    for (int nt = 0; nt < 16; ++nt) {
      bfrag8 qa = *(const bfrag8*)(u2p + (size_t)(16 * nt + lo) * D_FF + f0 + hi * 8);
      qacc[nt] = __builtin_amdgcn_mfma_f32_16x16x32_bf16(qa, bq, qacc[nt], 0, 0, 0);
    }
    __builtin_amdgcn_s_barrier();   // lockstep pacing only (no LDS, no waitcnt)
  }

  float* qp = qpart + (size_t)j * NROWS * RANK + row * RANK;
#pragma unroll
  for (int nt = 0; nt < 16; ++nt)
    *(fx4*)(qp + 16 * nt + 4 * hi) = qacc[nt];
}

// ---------------- out = (sum_j Qpart_j) @ V2 + b2 ----------------
__global__ __launch_bounds__(512, 4) void ogemm(
    const float* __restrict__ qpart, int F,
    const unsigned short* __restrict__ v2t,   // [D_MODEL][RANK]
    const float* __restrict__ b2,
    float* __restrict__ out)
{
  __shared__ unsigned short Qs[64 * PSTR];
  const int tid = threadIdx.x;
  const int w = tid >> 6, lane = tid & 63, lo = lane & 15, hi = lane >> 4;
  const int wm = w >> 2, wn = w & 3;
  const size_t gr0 = (size_t)blockIdx.x * 64;
  const int n0 = blockIdx.y * 256;

#pragma unroll
  for (int it = 0; it < 8; ++it) {
    int idx = it * 512 + tid;
    int r = idx >> 6, c = (idx & 63) << 2;
    fx4 s = *(const fx4*)(qpart + (gr0 + r) * RANK + c);
    for (int jj = 1; jj < F; ++jj) {
      fx4 s1 = *(const fx4*)(qpart + (size_t)jj * NROWS * RANK + (gr0 + r) * RANK + c);
      s[0] += s1[0]; s[1] += s1[1]; s[2] += s1[2]; s[3] += s1[3];
    }
    usx4 bv; bv[0] = f2b(s[0]); bv[1] = f2b(s[1]); bv[2] = f2b(s[2]); bv[3] = f2b(s[3]);
    *(usx4*)(Qs + r * PSTR + c) = bv;
  }
  __syncthreads();

  fx4 acc[2][4];
#pragma unroll
  for (int mt = 0; mt < 2; ++mt)
#pragma unroll
    for (int nt = 0; nt < 4; ++nt) acc[mt][nt] = fx4{0.f, 0.f, 0.f, 0.f};

#pragma unroll
  for (int ks = 0; ks < RANK; ks += 32) {
    bfrag8 a[2], b[4];
#pragma unroll
    for (int mt = 0; mt < 2; ++mt)
      a[mt] = *(const bfrag8*)(Qs + (wm * 32 + 16 * mt + lo) * PSTR + ks + hi * 8);
#pragma unroll
    for (int nt = 0; nt < 4; ++nt)
      b[nt] = *(const bfrag8*)(v2t + (size_t)(n0 + wn * 64 + nt * 16 + lo) * RANK + ks + hi * 8);
#pragma unroll
    for (int mt = 0; mt < 2; ++mt)
#pragma unroll
      for (int nt = 0; nt < 4; ++nt)
        acc[mt][nt] = __builtin_amdgcn_mfma_f32_16x16x32_bf16(a[mt], b[nt], acc[mt][nt], 0, 0, 0);
  }

#pragma unroll
  for (int nt = 0; nt < 4; ++nt) {
    int col = n0 + wn * 64 + nt * 16 + lo;
    float bias = b2[col];
#pragma unroll
    for (int mt = 0; mt < 2; ++mt)
#pragma unroll
      for (int r = 0; r < 4; ++r)
        out[(gr0 + wm * 32 + 16 * mt + 4 * hi + r) * D_MODEL + col] = acc[mt][nt][r] + bias;
  }
}

extern "C" void kernel_launch(void* const* d_in, const int* in_sizes, int n_in,
                              void* d_out, int out_size, void* d_ws, size_t ws_size,
                              hipStream_t stream) {
  const float* x  = (const float*)d_in[0];
  const float* U1 = (const float*)d_in[1];
  const float* V1 = (const float*)d_in[2];
  const float* b1 = (const float*)d_in[3];
  const float* U2 = (const float*)d_in[4];
  const float* V2 = (const float*)d_in[5];
  const float* b2 = (const float*)d_in[6];
  float* out = (float*)d_out;

  unsigned short* ws16 = (unsigned short*)d_ws;
  unsigned short* u1t = ws16;                                 // [256][1024]
  unsigned short* v1t = u1t + (size_t)RANK * D_MODEL;         // [4096][256]
  unsigned short* u2p = v1t + (size_t)D_FF * RANK;            // [256][4096] permuted
  unsigned short* v2t = u2p + (size_t)RANK * D_FF;            // [1024][256]
  unsigned short* Pbf = v2t + (size_t)D_MODEL * RANK;         // [16384][256] bf16
  float* qpart = (float*)(Pbf + (size_t)NROWS * RANK);        // [F][16384][256] f32

  size_t fixed_bytes = 2ull * ((size_t)RANK * D_MODEL + (size_t)D_FF * RANK +
                               (size_t)RANK * D_FF + (size_t)D_MODEL * RANK +
                               (size_t)NROWS * RANK);
  size_t qbytes = (size_t)NROWS * RANK * 4;
  int F = (ws_size >= fixed_bytes + 2 * qbytes) ? 2 : 1;

  tconv<<<dim3(RANK / 32, D_MODEL / 32), 256, 0, stream>>>(U1, u1t, D_MODEL, RANK);
  tconv<<<dim3(D_FF / 32, RANK / 32),   256, 0, stream>>>(V1, v1t, RANK, D_FF);
  u2repack<<<dim3(D_FF / 32, RANK / 32), 256, 0, stream>>>(U2, u2p);
  tconv<<<dim3(D_MODEL / 32, RANK / 32),256, 0, stream>>>(V2, v2t, RANK, D_MODEL);

  pgemm<<<NROWS / 32, 256, 0, stream>>>(x, u1t, Pbf);
  hqgemm<<<dim3(NROWS / 128, F), 512, 0, stream>>>(Pbf, v1t, b1, u2p, qpart, F);
  ogemm<<<dim3(NROWS / 64, D_MODEL / 256), 512, 0, stream>>>(qpart, F, v2t, b2, out);
}

// Round 6
// 238.765 us; speedup vs baseline: 2.6510x; 2.6510x over previous
//
#include <hip/hip_runtime.h>
#include <hip/hip_bf16.h>

// FlashSVDFFN: out = (gelu((x@U1)@V1 + b1)@U2)@V2 + b2
// pgemm: P = bf16(x)@U1  [16384][256] bf16
// hqgemm: fused H+Q, swapped-operand MFMA; H in registers (no LDS round trip);
//         weights LDS-staged in 64-f double-buffered chunks (T14 pipeline).
// ogemm: out = (sum_j qpart_j)@V2 + b2

typedef __attribute__((ext_vector_type(8))) short bfrag8;     // 8 bf16 fragment
typedef __attribute__((ext_vector_type(4))) float fx4;
typedef __attribute__((ext_vector_type(4))) unsigned short usx4;

#define D_MODEL 1024
#define D_FF    4096
#define RANK    256
#define NROWS   16384
#define PSTR    264        // [.][256] LDS stride (+8 pad)
#define XSTR    136        // [.][128] LDS stride (+8 pad)
#define VSTR    264        // v1 chunk LDS stride (256+8)
#define USTR    72         // u2 chunk LDS stride (64+8)

__device__ __forceinline__ unsigned short f2b(float f) {
  union { float f; unsigned u; } v; v.f = f;
  unsigned r = v.u + 0x7FFFu + ((v.u >> 16) & 1u);   // RTNE
  return (unsigned short)(r >> 16);
}

__device__ __forceinline__ float gelu_tanh(float x) {
  float x2 = x * x;
  float y  = 0.7978845608028654f * __builtin_fmaf(0.044715f * x2, x, x);
  float ay = __builtin_fabsf(y);
  float e  = __expf(-2.0f * ay);
  float t  = (1.0f - e) * __builtin_amdgcn_rcpf(1.0f + e);   // tanh(|y|)
  t = __builtin_copysignf(t, y);
  return 0.5f * x * (1.0f + t);
}

// out[c][r] = bf16(in[r][c]); in is R x C row-major.
__global__ void tconv(const float* __restrict__ in, unsigned short* __restrict__ out,
                      int R, int C) {
  __shared__ float t[32][33];
  int c0 = blockIdx.x * 32, r0 = blockIdx.y * 32;
  int tx = threadIdx.x & 31, ty = threadIdx.x >> 5;
#pragma unroll
  for (int i = 0; i < 32; i += 8)
    t[ty + i][tx] = in[(size_t)(r0 + ty + i) * C + c0 + tx];
  __syncthreads();
#pragma unroll
  for (int i = 0; i < 32; i += 8)
    out[(size_t)(c0 + ty + i) * R + r0 + tx] = f2b(t[tx][ty + i]);
}

// U2 [D_FF][RANK] f32 -> u2p [RANK][D_FF] bf16 with k-slot permutation
// u2p[r2][32t + 8hi + j] = U2[32t + (j>=4)*16 + 4hi + (j&3)][r2]
__global__ void u2repack(const float* __restrict__ in, unsigned short* __restrict__ out) {
  __shared__ float t[32][33];
  int f0 = blockIdx.x * 32, r0 = blockIdx.y * 32;
  int tx = threadIdx.x & 31, ty = threadIdx.x >> 5;
#pragma unroll
  for (int i = 0; i < 32; i += 8)
    t[ty + i][tx] = in[(size_t)(f0 + ty + i) * RANK + r0 + tx];
  __syncthreads();
  int fl = (((tx & 7) >= 4) ? 16 : 0) + 4 * (tx >> 3) + (tx & 3);
#pragma unroll
  for (int i = 0; i < 32; i += 8)
    out[(size_t)(r0 + ty + i) * D_FF + f0 + tx] = f2b(t[fl][ty + i]);
}

// ---------------- P = bf16(x) @ U1 : [16384][256] bf16 ----------------
__global__ __launch_bounds__(256, 4) void pgemm(
    const float* __restrict__ x, const unsigned short* __restrict__ u1t,
    unsigned short* __restrict__ P)
{
  __shared__ unsigned short xs[32 * XSTR];
  const int tid = threadIdx.x;
  const int w = tid >> 6, lane = tid & 63, lo = lane & 15, hi = lane >> 4;
  const size_t gr0 = (size_t)blockIdx.x * 32;

  fx4 acc[2][4];
#pragma unroll
  for (int mt = 0; mt < 2; ++mt)
#pragma unroll
    for (int nt = 0; nt < 4; ++nt) acc[mt][nt] = fx4{0.f, 0.f, 0.f, 0.f};

  for (int d0 = 0; d0 < D_MODEL; d0 += 128) {
    __syncthreads();
#pragma unroll
    for (int it = 0; it < 4; ++it) {
      int idx = it * 256 + tid;
      int r = idx >> 5, c = (idx & 31) << 2;
      fx4 v = *(const fx4*)(x + (gr0 + r) * D_MODEL + d0 + c);
      usx4 bv; bv[0] = f2b(v[0]); bv[1] = f2b(v[1]); bv[2] = f2b(v[2]); bv[3] = f2b(v[3]);
      *(usx4*)(xs + r * XSTR + c) = bv;
    }
    __syncthreads();
#pragma unroll
    for (int ks = 0; ks < 128; ks += 32) {
      bfrag8 a[2], b[4];
#pragma unroll
      for (int mt = 0; mt < 2; ++mt)
        a[mt] = *(const bfrag8*)(xs + (16 * mt + lo) * XSTR + ks + hi * 8);
#pragma unroll
      for (int nt = 0; nt < 4; ++nt)
        b[nt] = *(const bfrag8*)(u1t + (size_t)(w * 64 + nt * 16 + lo) * D_MODEL + d0 + ks + hi * 8);
#pragma unroll
      for (int mt = 0; mt < 2; ++mt)
#pragma unroll
        for (int nt = 0; nt < 4; ++nt)
          acc[mt][nt] = __builtin_amdgcn_mfma_f32_16x16x32_bf16(a[mt], b[nt], acc[mt][nt], 0, 0, 0);
    }
  }
#pragma unroll
  for (int mt = 0; mt < 2; ++mt)
#pragma unroll
    for (int nt = 0; nt < 4; ++nt)
#pragma unroll
      for (int r = 0; r < 4; ++r)
        P[(gr0 + 16 * mt + 4 * hi + r) * RANK + w * 64 + nt * 16 + lo] = f2b(acc[mt][nt][r]);
}

// -------- fused H+Q: swapped MFMA, H in regs, weights via LDS chunks --------
// 512 thr = 8 waves: wr=w>>1 (row-group, 32 rows), wc=w&1 (r2-half, 128 cols).
__global__ __launch_bounds__(512, 2) void hqgemm(
    const unsigned short* __restrict__ P,     // [NROWS][RANK] bf16
    const unsigned short* __restrict__ v1t,   // [D_FF][RANK] bf16 = V1^T
    const float* __restrict__ b1,
    const unsigned short* __restrict__ u2p,   // [RANK][D_FF] bf16, k-permuted
    float* __restrict__ qpart,                // [F][NROWS][RANK] f32
    int F)
{
  __shared__ unsigned short v1s[2][64 * VSTR];    // 67.6 KB: chunk rows f, cols k
  __shared__ unsigned short u2s[2][256 * USTR];   // 73.7 KB: rows r2, cols f(64)

  const int tid = threadIdx.x;
  const int w = tid >> 6, lane = tid & 63, lo = lane & 15, hi = lane >> 4;
  const int wr = w >> 1, wc = w & 1;

  int lin = blockIdx.x, j, rb;
  if (F == 2) { j = lin & 1; rb = lin >> 1; }     // parity -> disjoint XCD sets
  else        { j = 0; rb = lin; }
  const int fbase = j * (D_FF / F);
  const int nchunk = (D_FF / F) / 64;
  const int rowstart = rb * 128 + wr * 32;

  // P fragments (B-operand; lo -> row, k-slot 8hi+e), 2 row-subgroups.
  bfrag8 pf[2][8];
#pragma unroll
  for (int rg = 0; rg < 2; ++rg)
#pragma unroll
    for (int ks = 0; ks < 8; ++ks)
      pf[rg][ks] = *(const bfrag8*)(P + (size_t)(rowstart + 16 * rg + lo) * RANK + ks * 32 + hi * 8);

  fx4 qacc[2][8];
#pragma unroll
  for (int rg = 0; rg < 2; ++rg)
#pragma unroll
    for (int nt = 0; nt < 8; ++nt) qacc[rg][nt] = fx4{0.f, 0.f, 0.f, 0.f};

  // ---- chunk staging (64 f): each buffer = 16384 bf16 -> 4 passes x 16B/thread ----
  bfrag8 sv[4], su[4];
#define HQ_LOAD(C) do {                                                        \
    int f0_ = fbase + (C) * 64;                                                \
    _Pragma("unroll")                                                          \
    for (int p = 0; p < 4; ++p) {                                              \
      int u = tid + 512 * p;                                                   \
      sv[p] = *(const bfrag8*)(v1t + (size_t)(f0_ + (u >> 5)) * RANK + (u & 31) * 8); \
      su[p] = *(const bfrag8*)(u2p + (size_t)(u >> 3) * D_FF + f0_ + (u & 7) * 8);    \
    } } while (0)
#define HQ_STORE(B) do {                                                       \
    _Pragma("unroll")                                                          \
    for (int p = 0; p < 4; ++p) {                                              \
      int u = tid + 512 * p;                                                   \
      *(bfrag8*)(&v1s[B][(u >> 5) * VSTR + (u & 31) * 8]) = sv[p];             \
      *(bfrag8*)(&u2s[B][(u >> 3) * USTR + (u & 7) * 8]) = su[p];              \
    } } while (0)

  HQ_LOAD(0); HQ_STORE(0);
  if (nchunk > 1) HQ_LOAD(1);

  int cur = 0;
  for (int c = 0; c < nchunk; ++c) {
    __syncthreads();                    // buf[cur] staged & prev readers done
    const int f0g = fbase + c * 64;
#pragma unroll
    for (int fw = 0; fw < 64; fw += 32) {   // two 32-f windows per chunk
      fx4 hacc[2][2];                       // [f-tile][row-subgroup]
#pragma unroll
      for (int t = 0; t < 2; ++t)
#pragma unroll
        for (int rg = 0; rg < 2; ++rg) hacc[t][rg] = fx4{0.f, 0.f, 0.f, 0.f};
#pragma unroll
      for (int ks = 0; ks < 8; ++ks) {
        bfrag8 v0 = *(const bfrag8*)(&v1s[cur][(fw + lo) * VSTR + ks * 32 + hi * 8]);
        bfrag8 v1f = *(const bfrag8*)(&v1s[cur][(fw + 16 + lo) * VSTR + ks * 32 + hi * 8]);
        hacc[0][0] = __builtin_amdgcn_mfma_f32_16x16x32_bf16(v0, pf[0][ks], hacc[0][0], 0, 0, 0);
        hacc[0][1] = __builtin_amdgcn_mfma_f32_16x16x32_bf16(v0, pf[1][ks], hacc[0][1], 0, 0, 0);
        hacc[1][0] = __builtin_amdgcn_mfma_f32_16x16x32_bf16(v1f, pf[0][ks], hacc[1][0], 0, 0, 0);
        hacc[1][1] = __builtin_amdgcn_mfma_f32_16x16x32_bf16(v1f, pf[1][ks], hacc[1][1], 0, 0, 0);
      }
      // lane (lo,hi) of hacc[t][rg][r] = H[rowstart+16rg+lo][f0g+fw+16t+4hi+r]
      fx4 bE = *(const fx4*)(b1 + f0g + fw + 4 * hi);
      fx4 bO = *(const fx4*)(b1 + f0g + fw + 16 + 4 * hi);
      bfrag8 bq[2];
#pragma unroll
      for (int rg = 0; rg < 2; ++rg)
#pragma unroll
        for (int r = 0; r < 4; ++r) {
          bq[rg][r]     = (short)f2b(gelu_tanh(hacc[0][rg][r] + bE[r]));
          bq[rg][r + 4] = (short)f2b(gelu_tanh(hacc[1][rg][r] + bO[r]));
        }
#pragma unroll
      for (int nt = 0; nt < 8; ++nt) {
        bfrag8 qa = *(const bfrag8*)(&u2s[cur][(16 * (8 * wc + nt) + lo) * USTR + fw + hi * 8]);
        qacc[0][nt] = __builtin_amdgcn_mfma_f32_16x16x32_bf16(qa, bq[0], qacc[0][nt], 0, 0, 0);
        qacc[1][nt] = __builtin_amdgcn_mfma_f32_16x16x32_bf16(qa, bq[1], qacc[1][nt], 0, 0, 0);
      }
    }
    if (c + 1 < nchunk) {
      HQ_STORE(cur ^ 1);                // waits vmcnt for HQ_LOAD(c+1) regs
      if (c + 2 < nchunk) HQ_LOAD(c + 2);
    }
    cur ^= 1;
  }

  // qacc[rg][nt] lane (lo,hi): Q[rowstart+16rg+lo][128wc+16nt+4hi+r]
  float* qp = qpart + (size_t)j * NROWS * RANK;
#pragma unroll
  for (int rg = 0; rg < 2; ++rg) {
    size_t row = (size_t)(rowstart + 16 * rg + lo);
#pragma unroll
    for (int nt = 0; nt < 8; ++nt)
      *(fx4*)(qp + row * RANK + 128 * wc + 16 * nt + 4 * hi) = qacc[rg][nt];
  }
#undef HQ_LOAD
#undef HQ_STORE
}

// ---------------- out = (sum_j Qpart_j) @ V2 + b2 ----------------
__global__ __launch_bounds__(512, 4) void ogemm(
    const float* __restrict__ qpart, int F,
    const unsigned short* __restrict__ v2t,   // [D_MODEL][RANK]
    const float* __restrict__ b2,
    float* __restrict__ out)
{
  __shared__ unsigned short Qs[64 * PSTR];
  const int tid = threadIdx.x;
  const int w = tid >> 6, lane = tid & 63, lo = lane & 15, hi = lane >> 4;
  const int wm = w >> 2, wn = w & 3;
  const size_t gr0 = (size_t)blockIdx.x * 64;
  const int n0 = blockIdx.y * 256;

#pragma unroll
  for (int it = 0; it < 8; ++it) {
    int idx = it * 512 + tid;
    int r = idx >> 6, c = (idx & 63) << 2;
    fx4 s = *(const fx4*)(qpart + (gr0 + r) * RANK + c);
    for (int jj = 1; jj < F; ++jj) {
      fx4 s1 = *(const fx4*)(qpart + (size_t)jj * NROWS * RANK + (gr0 + r) * RANK + c);
      s[0] += s1[0]; s[1] += s1[1]; s[2] += s1[2]; s[3] += s1[3];
    }
    usx4 bv; bv[0] = f2b(s[0]); bv[1] = f2b(s[1]); bv[2] = f2b(s[2]); bv[3] = f2b(s[3]);
    *(usx4*)(Qs + r * PSTR + c) = bv;
  }
  __syncthreads();

  fx4 acc[2][4];
#pragma unroll
  for (int mt = 0; mt < 2; ++mt)
#pragma unroll
    for (int nt = 0; nt < 4; ++nt) acc[mt][nt] = fx4{0.f, 0.f, 0.f, 0.f};

#pragma unroll
  for (int ks = 0; ks < RANK; ks += 32) {
    bfrag8 a[2], b[4];
#pragma unroll
    for (int mt = 0; mt < 2; ++mt)
      a[mt] = *(const bfrag8*)(Qs + (wm * 32 + 16 * mt + lo) * PSTR + ks + hi * 8);
#pragma unroll
    for (int nt = 0; nt < 4; ++nt)
      b[nt] = *(const bfrag8*)(v2t + (size_t)(n0 + wn * 64 + nt * 16 + lo) * RANK + ks + hi * 8);
#pragma unroll
    for (int mt = 0; mt < 2; ++mt)
#pragma unroll
      for (int nt = 0; nt < 4; ++nt)
        acc[mt][nt] = __builtin_amdgcn_mfma_f32_16x16x32_bf16(a[mt], b[nt], acc[mt][nt], 0, 0, 0);
  }

#pragma unroll
  for (int nt = 0; nt < 4; ++nt) {
    int col = n0 + wn * 64 + nt * 16 + lo;
    float bias = b2[col];
#pragma unroll
    for (int mt = 0; mt < 2; ++mt)
#pragma unroll
      for (int r = 0; r < 4; ++r)
        out[(gr0 + wm * 32 + 16 * mt + 4 * hi + r) * D_MODEL + col] = acc[mt][nt][r] + bias;
  }
}

extern "C" void kernel_launch(void* const* d_in, const int* in_sizes, int n_in,
                              void* d_out, int out_size, void* d_ws, size_t ws_size,
                              hipStream_t stream) {
  const float* x  = (const float*)d_in[0];
  const float* U1 = (const float*)d_in[1];
  const float* V1 = (const float*)d_in[2];
  const float* b1 = (const float*)d_in[3];
  const float* U2 = (const float*)d_in[4];
  const float* V2 = (const float*)d_in[5];
  const float* b2 = (const float*)d_in[6];
  float* out = (float*)d_out;

  unsigned short* ws16 = (unsigned short*)d_ws;
  unsigned short* u1t = ws16;                                 // [256][1024]
  unsigned short* v1t = u1t + (size_t)RANK * D_MODEL;         // [4096][256]
  unsigned short* u2p = v1t + (size_t)D_FF * RANK;            // [256][4096] permuted
  unsigned short* v2t = u2p + (size_t)RANK * D_FF;            // [1024][256]
  unsigned short* Pbf = v2t + (size_t)D_MODEL * RANK;         // [16384][256] bf16
  float* qpart = (float*)(Pbf + (size_t)NROWS * RANK);        // [F][16384][256] f32

  size_t fixed_bytes = 2ull * ((size_t)RANK * D_MODEL + (size_t)D_FF * RANK +
                               (size_t)RANK * D_FF + (size_t)D_MODEL * RANK +
                               (size_t)NROWS * RANK);
  size_t qbytes = (size_t)NROWS * RANK * 4;
  int F = (ws_size >= fixed_bytes + 2 * qbytes) ? 2 : 1;

  tconv<<<dim3(RANK / 32, D_MODEL / 32), 256, 0, stream>>>(U1, u1t, D_MODEL, RANK);
  tconv<<<dim3(D_FF / 32, RANK / 32),   256, 0, stream>>>(V1, v1t, RANK, D_FF);
  u2repack<<<dim3(D_FF / 32, RANK / 32), 256, 0, stream>>>(U2, u2p);
  tconv<<<dim3(D_MODEL / 32, RANK / 32),256, 0, stream>>>(V2, v2t, RANK, D_MODEL);

  pgemm<<<NROWS / 32, 256, 0, stream>>>(x, u1t, Pbf);
  hqgemm<<<(NROWS / 128) * F, 512, 0, stream>>>(Pbf, v1t, b1, u2p, qpart, F);
  ogemm<<<dim3(NROWS / 64, D_MODEL / 256), 512, 0, stream>>>(qpart, F, v2t, b2, out);
}

// Round 9
// 202.455 us; speedup vs baseline: 3.1265x; 1.1793x over previous
//
#include <hip/hip_runtime.h>
#include <hip/hip_bf16.h>

// FlashSVDFFN: out = (gelu((x@U1)@V1 + b1)@U2)@V2 + b2
// pgemm: P = bf16(x)@U1  [16384][256] bf16
// hqgemm: fused H+Q, swapped-operand MFMA, no H duplication (wave = 32 rows x 256 r2),
//         weights DMA-staged (global_load_lds) from pre-swizzled chunk-contiguous
//         layouts, 32-f double-buffered chunks, F-way f-split.
// ogemm: out = (sum_j qpart_j)@V2 + b2

typedef __attribute__((ext_vector_type(8))) short bfrag8;     // 8 bf16 fragment
typedef __attribute__((ext_vector_type(4))) float fx4;
typedef __attribute__((ext_vector_type(4))) unsigned short usx4;

#define D_MODEL 1024
#define D_FF    4096
#define RANK    256
#define NROWS   16384
#define PSTR    264        // ogemm LDS stride (256+8)
#define XSTR    136        // pgemm LDS stride (128+8)

__device__ __forceinline__ unsigned short f2b(float f) {
  union { float f; unsigned u; } v; v.f = f;
  unsigned r = v.u + 0x7FFFu + ((v.u >> 16) & 1u);   // RTNE
  return (unsigned short)(r >> 16);
}

__device__ __forceinline__ float gelu_tanh(float x) {
  // 0.5x(1+tanh(0.79788456(x+0.044715x^3))), tanh(y)=1-2/(1+e^{2y})
  float x2 = x * x;
  float inner = __builtin_fmaf(0.044715f * x2, x, x);
  float e = __expf(1.5957691216057308f * inner);          // e^{2*0.79788456*inner}
  float t = __builtin_fmaf(-2.0f, __builtin_amdgcn_rcpf(1.0f + e), 1.0f);
  float hx = 0.5f * x;
  return __builtin_fmaf(hx, t, hx);
}

__device__ __forceinline__ void gl_lds16(const unsigned short* g, unsigned short* l) {
  __builtin_amdgcn_global_load_lds(
      (const __attribute__((address_space(1))) unsigned int*)g,
      (__attribute__((address_space(3))) unsigned int*)l, 16, 0, 0);
}

// out[c][r] = bf16(in[r][c]); in is R x C row-major. (used for U1, V2)
__global__ void tconv(const float* __restrict__ in, unsigned short* __restrict__ out,
                      int R, int C) {
  __shared__ float t[32][33];
  int c0 = blockIdx.x * 32, r0 = blockIdx.y * 32;
  int tx = threadIdx.x & 31, ty = threadIdx.x >> 5;
#pragma unroll
  for (int i = 0; i < 32; i += 8)
    t[ty + i][tx] = in[(size_t)(r0 + ty + i) * C + c0 + tx];
  __syncthreads();
#pragma unroll
  for (int i = 0; i < 32; i += 8)
    out[(size_t)(c0 + ty + i) * R + r0 + tx] = f2b(t[tx][ty + i]);
}

// V1 [RANK][D_FF] f32 -> v1c [D_FF][RANK] bf16, bank-swizzled:
// v1c[f][q] = V1[q ^ ((f&7)<<3)][f]  for q in [0,256)
// FIX (r8): XOR must apply to the FULL k index (k0+tx), not within the 32-block —
// swz bit 5 (value 32) crosses k-blocks; old code scrambled all f with f&4.
__global__ void v1pack(const float* __restrict__ in, unsigned short* __restrict__ out) {
  __shared__ float t[32][33];
  int f0 = blockIdx.x * 32, k0 = blockIdx.y * 32;
  int tx = threadIdx.x & 31, ty = threadIdx.x >> 5;
#pragma unroll
  for (int i = 0; i < 32; i += 8)
    t[ty + i][tx] = in[(size_t)(k0 + ty + i) * D_FF + f0 + tx];   // t[k_l][f_l]
  __syncthreads();
#pragma unroll
  for (int i = 0; i < 32; i += 8) {
    int f = ty + i;
    out[(size_t)(f0 + f) * RANK + ((k0 + tx) ^ ((f & 7) << 3))] = f2b(t[tx][f]);
  }
}

// U2 [D_FF][RANK] f32 -> u2c chunked [D_FF/32][256][32] bf16 with k-slot perm + swizzle:
// u2c[c][r2][q]: s = q ^ (((r2>>1)&3)<<3); pi(s) = ((s&7)>=4)*16 + 4*(s>>3) + (s&3);
// value = U2[c*32 + pi(s)][r2]   (swz <= 24: stays inside the 32-wide row)
__global__ void u2pack(const float* __restrict__ in, unsigned short* __restrict__ out) {
  __shared__ float t[32][33];
  int f0 = blockIdx.x * 32, r0 = blockIdx.y * 32;
  int cg = blockIdx.x;
  int tx = threadIdx.x & 31, ty = threadIdx.x >> 5;
#pragma unroll
  for (int i = 0; i < 32; i += 8)
    t[ty + i][tx] = in[(size_t)(f0 + ty + i) * RANK + r0 + tx];   // t[f_l][r2_l]
  __syncthreads();
#pragma unroll
  for (int i = 0; i < 32; i += 8) {
    int r2l = ty + i;
    int s = tx ^ (((r2l >> 1) & 3) << 3);
    int fl = (((s & 7) >= 4) ? 16 : 0) + 4 * (s >> 3) + (s & 3);
    out[(size_t)cg * 8192 + (size_t)(r0 + r2l) * 32 + tx] = f2b(t[fl][r2l]);
  }
}

// ---------------- P = bf16(x) @ U1 : [16384][256] bf16 ----------------
__global__ __launch_bounds__(256, 4) void pgemm(
    const float* __restrict__ x, const unsigned short* __restrict__ u1t,
    unsigned short* __restrict__ P)
{
  __shared__ unsigned short xs[32 * XSTR];
  const int tid = threadIdx.x;
  const int w = tid >> 6, lane = tid & 63, lo = lane & 15, hi = lane >> 4;
  const size_t gr0 = (size_t)blockIdx.x * 32;

  fx4 acc[2][4];
#pragma unroll
  for (int mt = 0; mt < 2; ++mt)
#pragma unroll
    for (int nt = 0; nt < 4; ++nt) acc[mt][nt] = fx4{0.f, 0.f, 0.f, 0.f};

  for (int d0 = 0; d0 < D_MODEL; d0 += 128) {
    __syncthreads();
#pragma unroll
    for (int it = 0; it < 4; ++it) {
      int idx = it * 256 + tid;
      int r = idx >> 5, c = (idx & 31) << 2;
      fx4 v = *(const fx4*)(x + (gr0 + r) * D_MODEL + d0 + c);
      usx4 bv; bv[0] = f2b(v[0]); bv[1] = f2b(v[1]); bv[2] = f2b(v[2]); bv[3] = f2b(v[3]);
      *(usx4*)(xs + r * XSTR + c) = bv;
    }
    __syncthreads();
#pragma unroll
    for (int ks = 0; ks < 128; ks += 32) {
      bfrag8 a[2], b[4];
#pragma unroll
      for (int mt = 0; mt < 2; ++mt)
        a[mt] = *(const bfrag8*)(xs + (16 * mt + lo) * XSTR + ks + hi * 8);
#pragma unroll
      for (int nt = 0; nt < 4; ++nt)
        b[nt] = *(const bfrag8*)(u1t + (size_t)(w * 64 + nt * 16 + lo) * D_MODEL + d0 + ks + hi * 8);
#pragma unroll
      for (int mt = 0; mt < 2; ++mt)
#pragma unroll
        for (int nt = 0; nt < 4; ++nt)
          acc[mt][nt] = __builtin_amdgcn_mfma_f32_16x16x32_bf16(a[mt], b[nt], acc[mt][nt], 0, 0, 0);
    }
  }
#pragma unroll
  for (int mt = 0; mt < 2; ++mt)
#pragma unroll
    for (int nt = 0; nt < 4; ++nt)
#pragma unroll
      for (int r = 0; r < 4; ++r)
        P[(gr0 + 16 * mt + 4 * hi + r) * RANK + w * 64 + nt * 16 + lo] = f2b(acc[mt][nt][r]);
}

// -------- fused H+Q: swapped MFMA, DMA-staged swizzled weights --------
// 256 thr = 4 waves, wave owns rows [rowstart, rowstart+32) x all 256 r2.
__global__ __launch_bounds__(256, 2) void hqgemm(
    const unsigned short* __restrict__ P,     // [NROWS][RANK] bf16
    const unsigned short* __restrict__ v1c,   // [D_FF][RANK] bf16 swizzled
    const float* __restrict__ b1,
    const unsigned short* __restrict__ u2c,   // [D_FF/32][256][32] bf16 perm+swz
    float* __restrict__ qpart,                // [F][NROWS][RANK] f32
    int F)
{
  __shared__ unsigned short v1s[2][32 * 256];   // 16 KB per buf
  __shared__ unsigned short u2s[2][256 * 32];   // 16 KB per buf

  const int tid = threadIdx.x;
  const int w = tid >> 6, lane = tid & 63, lo = lane & 15, hi = lane >> 4;

  int bid = blockIdx.x, j = 0, rb = bid;
  if (F == 4)      { j = bid & 3; rb = bid >> 2; }
  else if (F == 2) { j = bid & 1; rb = bid >> 1; }
  const int fbase = j * (D_FF / F);
  const int nchunk = (D_FF / F) / 32;
  const int rowstart = rb * 128 + w * 32;

  // P fragments (B-operand; lo -> x-row, k-slot 8hi+e), 2 row-subgroups.
  bfrag8 pf[2][8];
#pragma unroll
  for (int rg = 0; rg < 2; ++rg)
#pragma unroll
    for (int ks = 0; ks < 8; ++ks)
      pf[rg][ks] = *(const bfrag8*)(P + (size_t)(rowstart + 16 * rg + lo) * RANK + ks * 32 + hi * 8);

  fx4 qacc[2][16];
#pragma unroll
  for (int rg = 0; rg < 2; ++rg)
#pragma unroll
    for (int nt = 0; nt < 16; ++nt) qacc[rg][nt] = fx4{0.f, 0.f, 0.f, 0.f};

  const int vswz = (lo & 7) << 3;
  const int qoff = (hi * 8) ^ (((lo >> 1) & 3) << 3);
  const int vbase = lo * 256;

  // stage chunk 0 -> buf 0 (linear 16KB copies, data pre-swizzled in global)
  {
    const unsigned short* vsrc = v1c + (size_t)fbase * 256;
    const unsigned short* usrc = u2c + (size_t)(fbase >> 5) * 8192;
#pragma unroll
    for (int p = 0; p < 4; ++p) {
      int off = tid * 8 + p * 2048;
      gl_lds16(vsrc + off, &v1s[0][off]);
      gl_lds16(usrc + off, &u2s[0][off]);
    }
  }
  __syncthreads();

  int cur = 0;
  for (int c = 0; c < nchunk; ++c) {
    if (c + 1 < nchunk) {          // issue next-chunk DMA early (T14)
      const unsigned short* vsrc = v1c + (size_t)(fbase + (c + 1) * 32) * 256;
      const unsigned short* usrc = u2c + (size_t)((fbase >> 5) + c + 1) * 8192;
#pragma unroll
      for (int p = 0; p < 4; ++p) {
        int off = tid * 8 + p * 2048;
        gl_lds16(vsrc + off, &v1s[cur ^ 1][off]);
        gl_lds16(usrc + off, &u2s[cur ^ 1][off]);
      }
    }
    const unsigned short* vb = v1s[cur];
    const unsigned short* ub = u2s[cur];

    // H-GEMM window: hacc[t][rg] -> H[rows 16rg+lo][f = 16t + 4hi + r]
    fx4 hacc[2][2];
#pragma unroll
    for (int t = 0; t < 2; ++t)
#pragma unroll
      for (int rg = 0; rg < 2; ++rg) hacc[t][rg] = fx4{0.f, 0.f, 0.f, 0.f};
#pragma unroll
    for (int ks = 0; ks < 8; ++ks) {
      int ko = (ks * 32 + hi * 8) ^ vswz;
      bfrag8 vE = *(const bfrag8*)(vb + vbase + ko);
      bfrag8 vO = *(const bfrag8*)(vb + vbase + 4096 + ko);
      hacc[0][0] = __builtin_amdgcn_mfma_f32_16x16x32_bf16(vE, pf[0][ks], hacc[0][0], 0, 0, 0);
      hacc[0][1] = __builtin_amdgcn_mfma_f32_16x16x32_bf16(vE, pf[1][ks], hacc[0][1], 0, 0, 0);
      hacc[1][0] = __builtin_amdgcn_mfma_f32_16x16x32_bf16(vO, pf[0][ks], hacc[1][0], 0, 0, 0);
      hacc[1][1] = __builtin_amdgcn_mfma_f32_16x16x32_bf16(vO, pf[1][ks], hacc[1][1], 0, 0, 0);
    }

    // bias + gelu + bf16 pack -> B-frags (k-slot order matches u2c's pi)
    const int f0g = fbase + c * 32;
    fx4 bE = *(const fx4*)(b1 + f0g + 4 * hi);
    fx4 bO = *(const fx4*)(b1 + f0g + 16 + 4 * hi);
    bfrag8 bq0, bq1;
#pragma unroll
    for (int r = 0; r < 4; ++r) {
      bq0[r]     = (short)f2b(gelu_tanh(hacc[0][0][r] + bE[r]));
      bq0[r + 4] = (short)f2b(gelu_tanh(hacc[1][0][r] + bO[r]));
      bq1[r]     = (short)f2b(gelu_tanh(hacc[0][1][r] + bE[r]));
      bq1[r + 4] = (short)f2b(gelu_tanh(hacc[1][1][r] + bO[r]));
    }

    // Q-GEMM: all 256 r2 for this wave's 32 rows
#pragma unroll
    for (int nt = 0; nt < 16; ++nt) {
      bfrag8 qa = *(const bfrag8*)(ub + (16 * nt + lo) * 32 + qoff);
      qacc[0][nt] = __builtin_amdgcn_mfma_f32_16x16x32_bf16(qa, bq0, qacc[0][nt], 0, 0, 0);
      qacc[1][nt] = __builtin_amdgcn_mfma_f32_16x16x32_bf16(qa, bq1, qacc[1][nt], 0, 0, 0);
    }

    __syncthreads();   // drains DMA (vmcnt0) + readers done with buf[cur]
    cur ^= 1;
  }

  // qacc[rg][nt] lane (lo,hi): Q[rowstart+16rg+lo][16nt+4hi+r]
  float* qp = qpart + (size_t)j * NROWS * RANK;
#pragma unroll
  for (int rg = 0; rg < 2; ++rg) {
    size_t row = (size_t)(rowstart + 16 * rg + lo);
#pragma unroll
    for (int nt = 0; nt < 16; ++nt)
      *(fx4*)(qp + row * RANK + 16 * nt + 4 * hi) = qacc[rg][nt];
  }
}

// ---------------- out = (sum_j Qpart_j) @ V2 + b2 ----------------
__global__ __launch_bounds__(512, 4) void ogemm(
    const float* __restrict__ qpart, int F,
    const unsigned short* __restrict__ v2t,   // [D_MODEL][RANK]
    const float* __restrict__ b2,
    float* __restrict__ out)
{
  __shared__ unsigned short Qs[64 * PSTR];
  const int tid = threadIdx.x;
  const int w = tid >> 6, lane = tid & 63, lo = lane & 15, hi = lane >> 4;
  const int wm = w >> 2, wn = w & 3;
  const size_t gr0 = (size_t)blockIdx.x * 64;
  const int n0 = blockIdx.y * 256;

#pragma unroll
  for (int it = 0; it < 8; ++it) {
    int idx = it * 512 + tid;
    int r = idx >> 6, c = (idx & 63) << 2;
    fx4 s = *(const fx4*)(qpart + (gr0 + r) * RANK + c);
    for (int jj = 1; jj < F; ++jj) {
      fx4 s1 = *(const fx4*)(qpart + (size_t)jj * NROWS * RANK + (gr0 + r) * RANK + c);
      s[0] += s1[0]; s[1] += s1[1]; s[2] += s1[2]; s[3] += s1[3];
    }
    usx4 bv; bv[0] = f2b(s[0]); bv[1] = f2b(s[1]); bv[2] = f2b(s[2]); bv[3] = f2b(s[3]);
    *(usx4*)(Qs + r * PSTR + c) = bv;
  }
  __syncthreads();

  fx4 acc[2][4];
#pragma unroll
  for (int mt = 0; mt < 2; ++mt)
#pragma unroll
    for (int nt = 0; nt < 4; ++nt) acc[mt][nt] = fx4{0.f, 0.f, 0.f, 0.f};

#pragma unroll
  for (int ks = 0; ks < RANK; ks += 32) {
    bfrag8 a[2], b[4];
#pragma unroll
    for (int mt = 0; mt < 2; ++mt)
      a[mt] = *(const bfrag8*)(Qs + (wm * 32 + 16 * mt + lo) * PSTR + ks + hi * 8);
#pragma unroll
    for (int nt = 0; nt < 4; ++nt)
      b[nt] = *(const bfrag8*)(v2t + (size_t)(n0 + wn * 64 + nt * 16 + lo) * RANK + ks + hi * 8);
#pragma unroll
    for (int mt = 0; mt < 2; ++mt)
#pragma unroll
      for (int nt = 0; nt < 4; ++nt)
        acc[mt][nt] = __builtin_amdgcn_mfma_f32_16x16x32_bf16(a[mt], b[nt], acc[mt][nt], 0, 0, 0);
  }

#pragma unroll
  for (int nt = 0; nt < 4; ++nt) {
    int col = n0 + wn * 64 + nt * 16 + lo;
    float bias = b2[col];
#pragma unroll
    for (int mt = 0; mt < 2; ++mt)
#pragma unroll
      for (int r = 0; r < 4; ++r)
        out[(gr0 + wm * 32 + 16 * mt + 4 * hi + r) * D_MODEL + col] = acc[mt][nt][r] + bias;
  }
}

extern "C" void kernel_launch(void* const* d_in, const int* in_sizes, int n_in,
                              void* d_out, int out_size, void* d_ws, size_t ws_size,
                              hipStream_t stream) {
  const float* x  = (const float*)d_in[0];
  const float* U1 = (const float*)d_in[1];
  const float* V1 = (const float*)d_in[2];
  const float* b1 = (const float*)d_in[3];
  const float* U2 = (const float*)d_in[4];
  const float* V2 = (const float*)d_in[5];
  const float* b2 = (const float*)d_in[6];
  float* out = (float*)d_out;

  unsigned short* ws16 = (unsigned short*)d_ws;
  unsigned short* u1t = ws16;                                 // [256][1024]
  unsigned short* v1c = u1t + (size_t)RANK * D_MODEL;         // [4096][256] swz
  unsigned short* u2c = v1c + (size_t)D_FF * RANK;            // [128][256][32] chunked
  unsigned short* v2t = u2c + (size_t)RANK * D_FF;            // [1024][256]
  unsigned short* Pbf = v2t + (size_t)D_MODEL * RANK;         // [16384][256] bf16
  float* qpart = (float*)(Pbf + (size_t)NROWS * RANK);        // [F][16384][256] f32

  size_t fixed_bytes = 2ull * ((size_t)RANK * D_MODEL + (size_t)D_FF * RANK +
                               (size_t)RANK * D_FF + (size_t)D_MODEL * RANK +
                               (size_t)NROWS * RANK);
  size_t qbytes = (size_t)NROWS * RANK * 4;
  int F = 1;
  if      (ws_size >= fixed_bytes + 4 * qbytes) F = 4;
  else if (ws_size >= fixed_bytes + 2 * qbytes) F = 2;

  tconv<<<dim3(RANK / 32, D_MODEL / 32), 256, 0, stream>>>(U1, u1t, D_MODEL, RANK);
  v1pack<<<dim3(D_FF / 32, RANK / 32), 256, 0, stream>>>(V1, v1c);
  u2pack<<<dim3(D_FF / 32, RANK / 32), 256, 0, stream>>>(U2, u2c);
  tconv<<<dim3(D_MODEL / 32, RANK / 32), 256, 0, stream>>>(V2, v2t, RANK, D_MODEL);

  pgemm<<<NROWS / 32, 256, 0, stream>>>(x, u1t, Pbf);
  hqgemm<<<(NROWS / 128) * F, 256, 0, stream>>>(Pbf, v1c, b1, u2c, qpart, F);
  ogemm<<<dim3(NROWS / 64, D_MODEL / 256), 512, 0, stream>>>(qpart, F, v2t, b2, out);
}